// Round 1
// baseline (51.504 us; speedup 1.0000x reference)
//
#include <hip/hip_runtime.h>

typedef unsigned short ushort_t;
typedef __bf16 bf16x8 __attribute__((ext_vector_type(8)));
typedef float f32x4 __attribute__((ext_vector_type(4)));

#define AS1 __attribute__((address_space(1)))
#define AS3 __attribute__((address_space(3)))

__device__ __forceinline__ ushort_t f2bf(float f) {
    unsigned u = __builtin_bit_cast(unsigned, f);
    u = (u + 0x7fffu + ((u >> 16) & 1u)) >> 16;
    return (ushort_t)u;
}

__device__ __forceinline__ void async16(void* lds, const void* g) {
    __builtin_amdgcn_global_load_lds((const AS1 unsigned int*)g,
                                     (AS3 unsigned int*)lds, 16, 0, 0);
}

__device__ __forceinline__ void softmax2(const float* __restrict__ sig, float& s0, float& s1) {
    float a = sig[0], b = sig[1];
    float m = fmaxf(a, b);
    float e0 = __expf(a - m), e1 = __expf(b - m);
    float inv = 1.0f / (e0 + e1);
    s0 = e0 * inv; s1 = e1 * inv;
}

// ---------------- prep: W_core (mix of seed + toeplitz), stored TRANSPOSED as bf16 ----------------
// Wt[o][k] = bf16( s0*W_seed[k][o] + s1*W_toep[k][o] )
// W_toep[k][o] = (k>=o) ? W_seed[k-o][0] : W_seed[0][o-k]
__global__ __launch_bounds__(256) void prep_w_kernel(const float* __restrict__ Wseed,
                                                     const float* __restrict__ Wsig,
                                                     ushort_t* __restrict__ Wt) {
    int tid = blockIdx.x * 256 + threadIdx.x;   // 1M threads
    int o = tid >> 10, k = tid & 1023;
    float s0, s1; softmax2(Wsig, s0, s1);
    float wseed = Wseed[(k << 10) + o];
    float wtoep = (k >= o) ? Wseed[(k - o) << 10] : Wseed[o - k];
    Wt[(o << 10) + k] = f2bf(s0 * wseed + s1 * wtoep);
}

// ---------------- prep: x fp32 -> bf16 ----------------
__global__ __launch_bounds__(256) void prep_x_kernel(const float* __restrict__ x,
                                                     ushort_t* __restrict__ xb) {
    int i = blockIdx.x * 256 + threadIdx.x;     // 1M threads, 8 elems each
    const float4* xp = (const float4*)x + (size_t)i * 2;
    float4 a = xp[0], b = xp[1];
    uint4 r;
    r.x = (unsigned)f2bf(a.x) | ((unsigned)f2bf(a.y) << 16);
    r.y = (unsigned)f2bf(a.z) | ((unsigned)f2bf(a.w) << 16);
    r.z = (unsigned)f2bf(b.x) | ((unsigned)f2bf(b.y) << 16);
    r.w = (unsigned)f2bf(b.z) | ((unsigned)f2bf(b.w) << 16);
    ((uint4*)xb)[i] = r;
}

// ---------------- main GEMM: C = Xb @ Wt^T, fused bias + activation mixture ----------------
// 128x128 tile, BK=32, 4 waves (2x2), each wave 64x64 via 4x4 frags of 16x16x32 MFMA.
#define BM 128
#define BN 128
#define BK 32
#define NKT 32   // 1024 / 32

__global__ __launch_bounds__(256) void gemm_kernel(const ushort_t* __restrict__ Xb,
                                                   const ushort_t* __restrict__ Wt,
                                                   const float* __restrict__ bseed,
                                                   const float* __restrict__ bsig,
                                                   const float* __restrict__ asig,
                                                   float* __restrict__ out) {
    __shared__ ushort_t At[BM * BK];  // 8 KB
    __shared__ ushort_t Bt[BN * BK];  // 8 KB

    const int t = threadIdx.x;        // 0..255
    const int wv = t >> 6;
    const int lane = t & 63;
    const int bx = blockIdx.x;
    const int brow = (bx >> 3) * BM;  // 64 row-blocks
    const int bcol = (bx & 7) * BN;   // 8 col-blocks

    // staging mapping: thread t covers 8 contiguous bf16 (16B); 4 threads per 32-elem row
    const int r0 = t >> 2;            // 0..63
    const int kc = (t & 3) * 8;       // 0,8,16,24
    const ushort_t* gA0 = Xb + (size_t)(brow + r0) * 1024 + kc;
    const ushort_t* gA1 = Xb + (size_t)(brow + 64 + r0) * 1024 + kc;
    const ushort_t* gB0 = Wt + (size_t)(bcol + r0) * 1024 + kc;
    const ushort_t* gB1 = Wt + (size_t)(bcol + 64 + r0) * 1024 + kc;
    ushort_t* lA0 = At + wv * 512;          // wave-uniform LDS bases (lane*16B implicit)
    ushort_t* lA1 = At + 2048 + wv * 512;
    ushort_t* lB0 = Bt + wv * 512;
    ushort_t* lB1 = Bt + 2048 + wv * 512;

    f32x4 acc[4][4];
    #pragma unroll
    for (int i = 0; i < 4; ++i)
        #pragma unroll
        for (int j = 0; j < 4; ++j) acc[i][j] = (f32x4){0.f, 0.f, 0.f, 0.f};

    const int wr = (wv >> 1) * 64;    // wave row origin in tile
    const int wcn = (wv & 1) * 64;    // wave col origin in tile
    const int fr = lane & 15;         // fragment row/col within 16
    const int kg = (lane >> 4) * 8;   // k-group offset

    for (int kt = 0; kt < NKT; ++kt) {
        async16(lA0, gA0); async16(lA1, gA1);
        async16(lB0, gB0); async16(lB1, gB1);
        gA0 += BK; gA1 += BK; gB0 += BK; gB1 += BK;
        __syncthreads();              // drains vmcnt -> staged data visible

        bf16x8 af[4], bf[4];
        #pragma unroll
        for (int mi = 0; mi < 4; ++mi)
            af[mi] = *(const bf16x8*)&At[(wr + mi * 16 + fr) * BK + kg];
        #pragma unroll
        for (int ni = 0; ni < 4; ++ni)
            bf[ni] = *(const bf16x8*)&Bt[(wcn + ni * 16 + fr) * BK + kg];

        #pragma unroll
        for (int mi = 0; mi < 4; ++mi)
            #pragma unroll
            for (int ni = 0; ni < 4; ++ni)
                acc[mi][ni] = __builtin_amdgcn_mfma_f32_16x16x32_bf16(af[mi], bf[ni], acc[mi][ni], 0, 0, 0);

        __syncthreads();              // all reads done before next overwrite
    }

    // epilogue: bias (softmax(b_sig)[0] * b_seed) + activation mixture softmax(A_sig)
    float bs0, bs1, as0, as1;
    softmax2(bsig, bs0, bs1);
    softmax2(asig, as0, as1);

    #pragma unroll
    for (int ni = 0; ni < 4; ++ni) {
        int col = bcol + wcn + ni * 16 + fr;
        float bias = bs0 * bseed[col];
        #pragma unroll
        for (int mi = 0; mi < 4; ++mi) {
            int row = brow + wr + mi * 16 + (lane >> 4) * 4;
            #pragma unroll
            for (int r = 0; r < 4; ++r) {
                float v = acc[mi][ni][r] + bias;
                out[(size_t)(row + r) * 1024 + col] = as0 * v + as1 * fmaxf(v, 0.f);
            }
        }
    }
}

// ---------------- fallback (only if workspace too small): naive fp32 ----------------
__global__ __launch_bounds__(256) void naive_kernel(const float* __restrict__ x,
                                                    const float* __restrict__ Wseed,
                                                    const float* __restrict__ bseed,
                                                    const float* __restrict__ Wsig,
                                                    const float* __restrict__ bsig,
                                                    const float* __restrict__ asig,
                                                    float* __restrict__ out) {
    int idx = blockIdx.x * 256 + threadIdx.x;
    int b = idx >> 10, o = idx & 1023;
    float ws0, ws1, bs0, bs1, as0, as1;
    softmax2(Wsig, ws0, ws1);
    softmax2(bsig, bs0, bs1);
    softmax2(asig, as0, as1);
    float s = 0.f;
    const float* xr = x + (size_t)b * 1024;
    for (int k = 0; k < 1024; ++k) {
        float wt = (k >= o) ? Wseed[(size_t)(k - o) << 10] : Wseed[o - k];
        float wc = ws0 * Wseed[((size_t)k << 10) + o] + ws1 * wt;
        s += xr[k] * wc;
    }
    float v = s + bs0 * bseed[o];
    out[idx] = as0 * v + as1 * fmaxf(v, 0.f);
}

extern "C" void kernel_launch(void* const* d_in, const int* in_sizes, int n_in,
                              void* d_out, int out_size, void* d_ws, size_t ws_size,
                              hipStream_t stream) {
    const float* x     = (const float*)d_in[0];
    const float* Wseed = (const float*)d_in[1];
    const float* bseed = (const float*)d_in[2];
    const float* Wsig  = (const float*)d_in[3];
    const float* bsig  = (const float*)d_in[4];
    const float* Asig  = (const float*)d_in[5];
    float* out = (float*)d_out;

    const size_t need = (2u << 20) + (16u << 20) + 1024;
    if (ws_size < need) {
        // fallback: correct but slow
        naive_kernel<<<dim3(8192 * 1024 / 256), dim3(256), 0, stream>>>(
            x, Wseed, bseed, Wsig, bsig, Asig, out);
        return;
    }

    ushort_t* Wt = (ushort_t*)d_ws;                         // 2 MB: W_core^T bf16 [1024][1024]
    ushort_t* Xb = (ushort_t*)((char*)d_ws + (2u << 20));   // 16 MB: x bf16 [8192][1024]

    prep_w_kernel<<<dim3(4096), dim3(256), 0, stream>>>(Wseed, Wsig, Wt);
    prep_x_kernel<<<dim3(4096), dim3(256), 0, stream>>>(x, Xb);
    gemm_kernel<<<dim3(512), dim3(256), 0, stream>>>(Xb, Wt, bseed, bsig, Asig, out);
}

// Round 2
// 46.441 us; speedup vs baseline: 1.1090x; 1.1090x over previous
//
#include <hip/hip_runtime.h>

typedef unsigned short ushort_t;
typedef __bf16 bf16x8 __attribute__((ext_vector_type(8)));
typedef float f32x4 __attribute__((ext_vector_type(4)));

#define AS1 __attribute__((address_space(1)))
#define AS3 __attribute__((address_space(3)))

__device__ __forceinline__ ushort_t f2bf(float f) {
    unsigned u = __builtin_bit_cast(unsigned, f);
    u = (u + 0x7fffu + ((u >> 16) & 1u)) >> 16;
    return (ushort_t)u;
}

__device__ __forceinline__ void async16(void* lds, const void* g) {
    __builtin_amdgcn_global_load_lds((const AS1 unsigned int*)g,
                                     (AS3 unsigned int*)lds, 16, 0, 0);
}

__device__ __forceinline__ void softmax2(const float* __restrict__ sig, float& s0, float& s1) {
    float a = sig[0], b = sig[1];
    float m = fmaxf(a, b);
    float e0 = __expf(a - m), e1 = __expf(b - m);
    float inv = 1.0f / (e0 + e1);
    s0 = e0 * inv; s1 = e1 * inv;
}

// ---------------- merged prep: x->bf16 AND W_core^T bf16 in one dispatch ----------------
// blocks [0, 4096):    x fp32 [8192][1024] -> xb bf16, 8 elems/thread
// blocks [4096, 8192): Wt[o][k] = bf16( s0*W_seed[k][o] + s1*W_toep[k][o] )
//                      W_toep[k][o] = (k>=o) ? W_seed[k-o][0] : W_seed[0][o-k]
__global__ __launch_bounds__(256) void prep_kernel(const float* __restrict__ x,
                                                   const float* __restrict__ Wseed,
                                                   const float* __restrict__ Wsig,
                                                   ushort_t* __restrict__ xb,
                                                   ushort_t* __restrict__ Wt) {
    int b = blockIdx.x;
    if (b < 4096) {
        int i = b * 256 + threadIdx.x;          // 1M threads, 8 elems each
        const float4* xp = (const float4*)x + (size_t)i * 2;
        float4 a = xp[0], c = xp[1];
        uint4 r;
        r.x = (unsigned)f2bf(a.x) | ((unsigned)f2bf(a.y) << 16);
        r.y = (unsigned)f2bf(a.z) | ((unsigned)f2bf(a.w) << 16);
        r.z = (unsigned)f2bf(c.x) | ((unsigned)f2bf(c.y) << 16);
        r.w = (unsigned)f2bf(c.z) | ((unsigned)f2bf(c.w) << 16);
        ((uint4*)xb)[i] = r;
    } else {
        int tid = (b - 4096) * 256 + threadIdx.x;   // 1M threads
        int o = tid >> 10, k = tid & 1023;
        float s0, s1; softmax2(Wsig, s0, s1);
        float wseed = Wseed[(k << 10) + o];
        float wtoep = (k >= o) ? Wseed[(k - o) << 10] : Wseed[o - k];
        Wt[(o << 10) + k] = f2bf(s0 * wseed + s1 * wtoep);
    }
}

// ---------------- main GEMM: C = Xb @ Wt^T, fused bias + activation mixture ----------------
// 128x128 tile, BK=32, 4 waves (2x2), each wave 64x64 via 4x4 frags of 16x16x32 MFMA.
// XCD swizzle: orig%8 = XCD (round-robin dispatch); each XCD owns 8 row-blocks x all
// 8 col-blocks -> per-XCD L2 working set = Xb panel (2MB) + full Wt (2MB) = 4MB (fits).
#define BM 128
#define BN 128
#define BK 32
#define NKT 32   // 1024 / 32

__global__ __launch_bounds__(256) void gemm_kernel(const ushort_t* __restrict__ Xb,
                                                   const ushort_t* __restrict__ Wt,
                                                   const float* __restrict__ bseed,
                                                   const float* __restrict__ bsig,
                                                   const float* __restrict__ asig,
                                                   float* __restrict__ out) {
    __shared__ ushort_t At[BM * BK];  // 8 KB
    __shared__ ushort_t Bt[BN * BK];  // 8 KB

    const int t = threadIdx.x;        // 0..255
    const int wv = t >> 6;
    const int lane = t & 63;

    // XCD-aware swizzle (512 blocks, 512%8==0 -> bijective)
    const int orig = blockIdx.x;
    const int g = orig & 7;           // XCD id under round-robin dispatch
    const int within = orig >> 3;     // 0..63 within this XCD
    const int rb = g * 8 + (within >> 3);   // row-block 0..63 (8 per XCD, contiguous)
    const int cb = within & 7;              // col-block 0..7 (all cols per XCD)
    const int brow = rb * BM;
    const int bcol = cb * BN;

    // staging mapping: thread t covers 8 contiguous bf16 (16B); 4 threads per 32-elem row
    const int r0 = t >> 2;            // 0..63
    const int kc = (t & 3) * 8;       // 0,8,16,24
    const ushort_t* gA0 = Xb + (size_t)(brow + r0) * 1024 + kc;
    const ushort_t* gA1 = Xb + (size_t)(brow + 64 + r0) * 1024 + kc;
    const ushort_t* gB0 = Wt + (size_t)(bcol + r0) * 1024 + kc;
    const ushort_t* gB1 = Wt + (size_t)(bcol + 64 + r0) * 1024 + kc;
    ushort_t* lA0 = At + wv * 512;          // wave-uniform LDS bases (lane*16B implicit)
    ushort_t* lA1 = At + 2048 + wv * 512;
    ushort_t* lB0 = Bt + wv * 512;
    ushort_t* lB1 = Bt + 2048 + wv * 512;

    f32x4 acc[4][4];
    #pragma unroll
    for (int i = 0; i < 4; ++i)
        #pragma unroll
        for (int j = 0; j < 4; ++j) acc[i][j] = (f32x4){0.f, 0.f, 0.f, 0.f};

    const int wr = (wv >> 1) * 64;    // wave row origin in tile
    const int wcn = (wv & 1) * 64;    // wave col origin in tile
    const int fr = lane & 15;         // fragment row/col within 16
    const int kg = (lane >> 4) * 8;   // k-group offset

    for (int kt = 0; kt < NKT; ++kt) {
        async16(lA0, gA0); async16(lA1, gA1);
        async16(lB0, gB0); async16(lB1, gB1);
        gA0 += BK; gA1 += BK; gB0 += BK; gB1 += BK;
        __syncthreads();              // drains vmcnt -> staged data visible

        bf16x8 af[4], bf[4];
        #pragma unroll
        for (int mi = 0; mi < 4; ++mi)
            af[mi] = *(const bf16x8*)&At[(wr + mi * 16 + fr) * BK + kg];
        #pragma unroll
        for (int ni = 0; ni < 4; ++ni)
            bf[ni] = *(const bf16x8*)&Bt[(wcn + ni * 16 + fr) * BK + kg];

        #pragma unroll
        for (int mi = 0; mi < 4; ++mi)
            #pragma unroll
            for (int ni = 0; ni < 4; ++ni)
                acc[mi][ni] = __builtin_amdgcn_mfma_f32_16x16x32_bf16(af[mi], bf[ni], acc[mi][ni], 0, 0, 0);

        __syncthreads();              // all reads done before next overwrite
    }

    // epilogue: bias (softmax(b_sig)[0] * b_seed) + activation mixture softmax(A_sig)
    float bs0, bs1, as0, as1;
    softmax2(bsig, bs0, bs1);
    softmax2(asig, as0, as1);

    #pragma unroll
    for (int ni = 0; ni < 4; ++ni) {
        int col = bcol + wcn + ni * 16 + fr;
        float bias = bs0 * bseed[col];
        #pragma unroll
        for (int mi = 0; mi < 4; ++mi) {
            int row = brow + wr + mi * 16 + (lane >> 4) * 4;
            #pragma unroll
            for (int r = 0; r < 4; ++r) {
                float v = acc[mi][ni][r] + bias;
                out[(size_t)(row + r) * 1024 + col] = as0 * v + as1 * fmaxf(v, 0.f);
            }
        }
    }
}

// ---------------- fallback (only if workspace too small): naive fp32 ----------------
__global__ __launch_bounds__(256) void naive_kernel(const float* __restrict__ x,
                                                    const float* __restrict__ Wseed,
                                                    const float* __restrict__ bseed,
                                                    const float* __restrict__ Wsig,
                                                    const float* __restrict__ bsig,
                                                    const float* __restrict__ asig,
                                                    float* __restrict__ out) {
    int idx = blockIdx.x * 256 + threadIdx.x;
    int b = idx >> 10, o = idx & 1023;
    float ws0, ws1, bs0, bs1, as0, as1;
    softmax2(Wsig, ws0, ws1);
    softmax2(bsig, bs0, bs1);
    softmax2(asig, as0, as1);
    float s = 0.f;
    const float* xr = x + (size_t)b * 1024;
    for (int k = 0; k < 1024; ++k) {
        float wt = (k >= o) ? Wseed[(size_t)(k - o) << 10] : Wseed[o - k];
        float wc = ws0 * Wseed[((size_t)k << 10) + o] + ws1 * wt;
        s += xr[k] * wc;
    }
    float v = s + bs0 * bseed[o];
    out[idx] = as0 * v + as1 * fmaxf(v, 0.f);
}

extern "C" void kernel_launch(void* const* d_in, const int* in_sizes, int n_in,
                              void* d_out, int out_size, void* d_ws, size_t ws_size,
                              hipStream_t stream) {
    const float* x     = (const float*)d_in[0];
    const float* Wseed = (const float*)d_in[1];
    const float* bseed = (const float*)d_in[2];
    const float* Wsig  = (const float*)d_in[3];
    const float* bsig  = (const float*)d_in[4];
    const float* Asig  = (const float*)d_in[5];
    float* out = (float*)d_out;

    const size_t need = (2u << 20) + (16u << 20) + 1024;
    if (ws_size < need) {
        // fallback: correct but slow
        naive_kernel<<<dim3(8192 * 1024 / 256), dim3(256), 0, stream>>>(
            x, Wseed, bseed, Wsig, bsig, Asig, out);
        return;
    }

    ushort_t* Wt = (ushort_t*)d_ws;                         // 2 MB: W_core^T bf16 [1024][1024]
    ushort_t* Xb = (ushort_t*)((char*)d_ws + (2u << 20));   // 16 MB: x bf16 [8192][1024]

    prep_kernel<<<dim3(8192), dim3(256), 0, stream>>>(x, Wseed, Wsig, Xb, Wt);
    gemm_kernel<<<dim3(512), dim3(256), 0, stream>>>(Xb, Wt, bseed, bsig, Asig, out);
}

// Round 3
// 46.085 us; speedup vs baseline: 1.1176x; 1.0077x over previous
//
#include <hip/hip_runtime.h>

typedef unsigned short ushort_t;
typedef __bf16 bf16x8 __attribute__((ext_vector_type(8)));
typedef float f32x4 __attribute__((ext_vector_type(4)));

#define AS1 __attribute__((address_space(1)))
#define AS3 __attribute__((address_space(3)))

__device__ __forceinline__ ushort_t f2bf(float f) {
    unsigned u = __builtin_bit_cast(unsigned, f);
    u = (u + 0x7fffu + ((u >> 16) & 1u)) >> 16;
    return (ushort_t)u;
}

__device__ __forceinline__ void async16(void* lds, const void* g) {
    __builtin_amdgcn_global_load_lds((const AS1 unsigned int*)g,
                                     (AS3 unsigned int*)lds, 16, 0, 0);
}

__device__ __forceinline__ void softmax2(const float* __restrict__ sig, float& s0, float& s1) {
    float a = sig[0], b = sig[1];
    float m = fmaxf(a, b);
    float e0 = __expf(a - m), e1 = __expf(b - m);
    float inv = 1.0f / (e0 + e1);
    s0 = e0 * inv; s1 = e1 * inv;
}

// toeplitz value: W_toep[k][o] = seed_vec[k-o+1023];
// d<=1022 -> Wseed[0][1023-d] ; d>=1023 -> Wseed[d-1023][0]
__device__ __forceinline__ float toep_val(const float* __restrict__ Wseed, int k, int o) {
    return (k >= o) ? Wseed[(size_t)(k - o) << 10] : Wseed[o - k];
}

// ---------------- merged prep ----------------
// blocks [0, 4096):    x fp32 [8192][1024] -> xb bf16, 8 elems/thread (coalesced)
// blocks [4096, 4352): 256 blocks, each a 64x64 (k,o) tile of W:
//   read Wseed rows coalesced, transpose via LDS, write Wt[o][k] bf16 coalesced.
__global__ __launch_bounds__(256) void prep_kernel(const float* __restrict__ x,
                                                   const float* __restrict__ Wseed,
                                                   const float* __restrict__ Wsig,
                                                   ushort_t* __restrict__ xb,
                                                   ushort_t* __restrict__ Wt) {
    int b = blockIdx.x;
    if (b < 4096) {
        int i = b * 256 + threadIdx.x;          // 1M threads, 8 elems each
        const float4* xp = (const float4*)x + (size_t)i * 2;
        float4 a = xp[0], c = xp[1];
        uint4 r;
        r.x = (unsigned)f2bf(a.x) | ((unsigned)f2bf(a.y) << 16);
        r.y = (unsigned)f2bf(a.z) | ((unsigned)f2bf(a.w) << 16);
        r.z = (unsigned)f2bf(c.x) | ((unsigned)f2bf(c.y) << 16);
        r.w = (unsigned)f2bf(c.z) | ((unsigned)f2bf(c.w) << 16);
        ((uint4*)xb)[i] = r;
        return;
    }
    // ---- W transpose tile ----
    __shared__ float T[64][65];                 // [k-within][o-within], padded
    int bb = b - 4096;                          // 0..255
    int k0 = (bb >> 4) * 64;
    int o0 = (bb & 15) * 64;
    int t = threadIdx.x;
    // load 64 rows x 64 cols of Wseed, coalesced (float4 along o)
    #pragma unroll
    for (int i = 0; i < 4; ++i) {
        int lin = t + i * 256;                  // 0..1023
        int kr = lin >> 4;                      // 0..63
        int c4 = lin & 15;                      // 0..15
        float4 v = *(const float4*)&Wseed[(size_t)(k0 + kr) * 1024 + o0 + c4 * 4];
        T[kr][c4 * 4 + 0] = v.x;   // note: stored as T[k][o]
        T[kr][c4 * 4 + 1] = v.y;
        T[kr][c4 * 4 + 2] = v.z;
        T[kr][c4 * 4 + 3] = v.w;
    }
    __syncthreads();
    float s0, s1; softmax2(Wsig, s0, s1);
    // write Wt[o][k] coalesced: 64 o-rows x 64 k as bf16 -> 512 uint4, 2 per thread
    #pragma unroll
    for (int i = 0; i < 2; ++i) {
        int lin = t + i * 256;                  // 0..511
        int oo = lin >> 3;                      // 0..63
        int kq = (lin & 7) * 8;                 // 0,8,..,56
        unsigned r[4];
        #pragma unroll
        for (int q = 0; q < 4; ++q) {
            float v0 = s0 * T[kq + 2 * q + 0][oo] + s1 * toep_val(Wseed, k0 + kq + 2 * q + 0, o0 + oo);
            float v1 = s0 * T[kq + 2 * q + 1][oo] + s1 * toep_val(Wseed, k0 + kq + 2 * q + 1, o0 + oo);
            r[q] = (unsigned)f2bf(v0) | ((unsigned)f2bf(v1) << 16);
        }
        *(uint4*)&Wt[(size_t)(o0 + oo) * 1024 + k0 + kq] = make_uint4(r[0], r[1], r[2], r[3]);
    }
}

// ---------------- main GEMM: C = Xb @ Wt^T, fused bias + activation mixture ----------------
// 64x128 tile, BK=32, grid 1024 -> 4 blocks/CU (occupancy was the R2 limiter).
// 4 waves (2x2), each wave 32x64 via 2x4 frags of 16x16x32 MFMA.
// XCD swizzle: each XCD owns 16 row-blocks x all 8 col-blocks ->
// per-XCD L2 set = Xb panel (2MB) + full Wt (2MB) = 4MB (fits).
#define BM 64
#define BN 128
#define BK 32
#define NKT 32   // 1024 / 32

__global__ __launch_bounds__(256, 4) void gemm_kernel(const ushort_t* __restrict__ Xb,
                                                      const ushort_t* __restrict__ Wt,
                                                      const float* __restrict__ bseed,
                                                      const float* __restrict__ bsig,
                                                      const float* __restrict__ asig,
                                                      float* __restrict__ out) {
    __shared__ ushort_t At[BM * BK];  // 4 KB
    __shared__ ushort_t Bt[BN * BK];  // 8 KB

    const int t = threadIdx.x;        // 0..255
    const int wv = t >> 6;
    const int lane = t & 63;

    // XCD-aware swizzle (1024 blocks, 1024%8==0 -> bijective)
    const int orig = blockIdx.x;
    const int g = orig & 7;           // XCD id under round-robin dispatch
    const int within = orig >> 3;     // 0..127 within this XCD
    const int rb = g * 16 + (within >> 3);  // row-block 0..127 (16 per XCD, contiguous)
    const int cb = within & 7;              // col-block 0..7 (all cols per XCD)
    const int brow = rb * BM;
    const int bcol = cb * BN;

    // staging: thread t covers 8 contiguous bf16 (16B); 4 threads per 32-elem row
    const int r0 = t >> 2;            // 0..63
    const int kc = (t & 3) * 8;       // 0,8,16,24
    const ushort_t* gA0 = Xb + (size_t)(brow + r0) * 1024 + kc;       // A: 64 rows
    const ushort_t* gB0 = Wt + (size_t)(bcol + r0) * 1024 + kc;       // B: rows 0..63
    const ushort_t* gB1 = Wt + (size_t)(bcol + 64 + r0) * 1024 + kc;  // B: rows 64..127
    ushort_t* lA0 = At + wv * 512;          // wave-uniform LDS bases (lane*16B implicit)
    ushort_t* lB0 = Bt + wv * 512;
    ushort_t* lB1 = Bt + 2048 + wv * 512;

    f32x4 acc[2][4];
    #pragma unroll
    for (int i = 0; i < 2; ++i)
        #pragma unroll
        for (int j = 0; j < 4; ++j) acc[i][j] = (f32x4){0.f, 0.f, 0.f, 0.f};

    const int wr = (wv >> 1) * 32;    // wave row origin in tile (0 or 32)
    const int wcn = (wv & 1) * 64;    // wave col origin in tile (0 or 64)
    const int fr = lane & 15;         // fragment row/col within 16
    const int kg = (lane >> 4) * 8;   // k-group offset

    for (int kt = 0; kt < NKT; ++kt) {
        async16(lA0, gA0);
        async16(lB0, gB0); async16(lB1, gB1);
        gA0 += BK; gB0 += BK; gB1 += BK;
        __syncthreads();              // drains vmcnt -> staged data visible

        bf16x8 af[2], bf[4];
        #pragma unroll
        for (int mi = 0; mi < 2; ++mi)
            af[mi] = *(const bf16x8*)&At[(wr + mi * 16 + fr) * BK + kg];
        #pragma unroll
        for (int ni = 0; ni < 4; ++ni)
            bf[ni] = *(const bf16x8*)&Bt[(wcn + ni * 16 + fr) * BK + kg];

        #pragma unroll
        for (int mi = 0; mi < 2; ++mi)
            #pragma unroll
            for (int ni = 0; ni < 4; ++ni)
                acc[mi][ni] = __builtin_amdgcn_mfma_f32_16x16x32_bf16(af[mi], bf[ni], acc[mi][ni], 0, 0, 0);

        __syncthreads();              // all reads done before next overwrite
    }

    // epilogue: bias (softmax(b_sig)[0] * b_seed) + activation mixture softmax(A_sig)
    float bs0, bs1, as0, as1;
    softmax2(bsig, bs0, bs1);
    softmax2(asig, as0, as1);

    #pragma unroll
    for (int ni = 0; ni < 4; ++ni) {
        int col = bcol + wcn + ni * 16 + fr;
        float bias = bs0 * bseed[col];
        #pragma unroll
        for (int mi = 0; mi < 2; ++mi) {
            int row = brow + wr + mi * 16 + (lane >> 4) * 4;
            #pragma unroll
            for (int r = 0; r < 4; ++r) {
                float v = acc[mi][ni][r] + bias;
                out[(size_t)(row + r) * 1024 + col] = as0 * v + as1 * fmaxf(v, 0.f);
            }
        }
    }
}

// ---------------- fallback (only if workspace too small): naive fp32 ----------------
__global__ __launch_bounds__(256) void naive_kernel(const float* __restrict__ x,
                                                    const float* __restrict__ Wseed,
                                                    const float* __restrict__ bseed,
                                                    const float* __restrict__ Wsig,
                                                    const float* __restrict__ bsig,
                                                    const float* __restrict__ asig,
                                                    float* __restrict__ out) {
    int idx = blockIdx.x * 256 + threadIdx.x;
    int b = idx >> 10, o = idx & 1023;
    float ws0, ws1, bs0, bs1, as0, as1;
    softmax2(Wsig, ws0, ws1);
    softmax2(bsig, bs0, bs1);
    softmax2(asig, as0, as1);
    float s = 0.f;
    const float* xr = x + (size_t)b * 1024;
    for (int k = 0; k < 1024; ++k) {
        float wc = ws0 * Wseed[((size_t)k << 10) + o] + ws1 * toep_val(Wseed, k, o);
        s += xr[k] * wc;
    }
    float v = s + bs0 * bseed[o];
    out[idx] = as0 * v + as1 * fmaxf(v, 0.f);
}

extern "C" void kernel_launch(void* const* d_in, const int* in_sizes, int n_in,
                              void* d_out, int out_size, void* d_ws, size_t ws_size,
                              hipStream_t stream) {
    const float* x     = (const float*)d_in[0];
    const float* Wseed = (const float*)d_in[1];
    const float* bseed = (const float*)d_in[2];
    const float* Wsig  = (const float*)d_in[3];
    const float* bsig  = (const float*)d_in[4];
    const float* Asig  = (const float*)d_in[5];
    float* out = (float*)d_out;

    const size_t need = (2u << 20) + (16u << 20) + 1024;
    if (ws_size < need) {
        naive_kernel<<<dim3(8192 * 1024 / 256), dim3(256), 0, stream>>>(
            x, Wseed, bseed, Wsig, bsig, Asig, out);
        return;
    }

    ushort_t* Wt = (ushort_t*)d_ws;                         // 2 MB: W_core^T bf16 [1024][1024]
    ushort_t* Xb = (ushort_t*)((char*)d_ws + (2u << 20));   // 16 MB: x bf16 [8192][1024]

    prep_kernel<<<dim3(4096 + 256), dim3(256), 0, stream>>>(x, Wseed, Wsig, Xb, Wt);
    gemm_kernel<<<dim3(1024), dim3(256), 0, stream>>>(Xb, Wt, bseed, bsig, Asig, out);
}

// Round 4
// 42.929 us; speedup vs baseline: 1.1997x; 1.0735x over previous
//
#include <hip/hip_runtime.h>

typedef unsigned short ushort_t;
typedef __bf16 bf16x8 __attribute__((ext_vector_type(8)));
typedef float f32x4 __attribute__((ext_vector_type(4)));

#define AS1 __attribute__((address_space(1)))
#define AS3 __attribute__((address_space(3)))

__device__ __forceinline__ ushort_t f2bf(float f) {
    unsigned u = __builtin_bit_cast(unsigned, f);
    u = (u + 0x7fffu + ((u >> 16) & 1u)) >> 16;
    return (ushort_t)u;
}

__device__ __forceinline__ void async16(void* lds, const void* g) {
    __builtin_amdgcn_global_load_lds((const AS1 unsigned int*)g,
                                     (AS3 unsigned int*)lds, 16, 0, 0);
}

__device__ __forceinline__ void softmax2(const float* __restrict__ sig, float& s0, float& s1) {
    float a = sig[0], b = sig[1];
    float m = fmaxf(a, b);
    float e0 = __expf(a - m), e1 = __expf(b - m);
    float inv = 1.0f / (e0 + e1);
    s0 = e0 * inv; s1 = e1 * inv;
}

// toeplitz value: W_toep[k][o]
__device__ __forceinline__ float toep_val(const float* __restrict__ Wseed, int k, int o) {
    return (k >= o) ? Wseed[(size_t)(k - o) << 10] : Wseed[o - k];
}

// ---------------- merged prep ----------------
// blocks [0, 4096):    x fp32 [8192][1024] -> xb bf16, 8 elems/thread (coalesced)
// blocks [4096, 4352): 256 blocks, each a 64x64 (k,o) tile of W:
//   read Wseed rows coalesced, transpose via LDS, write Wt[o][k] bf16 coalesced.
__global__ __launch_bounds__(256) void prep_kernel(const float* __restrict__ x,
                                                   const float* __restrict__ Wseed,
                                                   const float* __restrict__ Wsig,
                                                   ushort_t* __restrict__ xb,
                                                   ushort_t* __restrict__ Wt) {
    int b = blockIdx.x;
    if (b < 4096) {
        int i = b * 256 + threadIdx.x;          // 1M threads, 8 elems each
        const float4* xp = (const float4*)x + (size_t)i * 2;
        float4 a = xp[0], c = xp[1];
        uint4 r;
        r.x = (unsigned)f2bf(a.x) | ((unsigned)f2bf(a.y) << 16);
        r.y = (unsigned)f2bf(a.z) | ((unsigned)f2bf(a.w) << 16);
        r.z = (unsigned)f2bf(c.x) | ((unsigned)f2bf(c.y) << 16);
        r.w = (unsigned)f2bf(c.z) | ((unsigned)f2bf(c.w) << 16);
        ((uint4*)xb)[i] = r;
        return;
    }
    // ---- W transpose tile ----
    __shared__ float T[64][65];                 // [k-within][o-within], padded
    int bb = b - 4096;                          // 0..255
    int k0 = (bb >> 4) * 64;
    int o0 = (bb & 15) * 64;
    int t = threadIdx.x;
    #pragma unroll
    for (int i = 0; i < 4; ++i) {
        int lin = t + i * 256;                  // 0..1023
        int kr = lin >> 4;                      // 0..63
        int c4 = lin & 15;                      // 0..15
        float4 v = *(const float4*)&Wseed[(size_t)(k0 + kr) * 1024 + o0 + c4 * 4];
        T[kr][c4 * 4 + 0] = v.x;
        T[kr][c4 * 4 + 1] = v.y;
        T[kr][c4 * 4 + 2] = v.z;
        T[kr][c4 * 4 + 3] = v.w;
    }
    __syncthreads();
    float s0, s1; softmax2(Wsig, s0, s1);
    #pragma unroll
    for (int i = 0; i < 2; ++i) {
        int lin = t + i * 256;                  // 0..511
        int oo = lin >> 3;                      // 0..63
        int kq = (lin & 7) * 8;                 // 0,8,..,56
        unsigned r[4];
        #pragma unroll
        for (int q = 0; q < 4; ++q) {
            float v0 = s0 * T[kq + 2 * q + 0][oo] + s1 * toep_val(Wseed, k0 + kq + 2 * q + 0, o0 + oo);
            float v1 = s0 * T[kq + 2 * q + 1][oo] + s1 * toep_val(Wseed, k0 + kq + 2 * q + 1, o0 + oo);
            r[q] = (unsigned)f2bf(v0) | ((unsigned)f2bf(v1) << 16);
        }
        *(uint4*)&Wt[(size_t)(o0 + oo) * 1024 + k0 + kq] = make_uint4(r[0], r[1], r[2], r[3]);
    }
}

// ---------------- main GEMM: C = Xb @ Wt^T, fused bias + activation mixture ----------------
// 128x128 tile, BK=32, grid 512, double-buffered LDS, ONE barrier per K-step
// (T3-minimum): stage(t+1) issued BEFORE compute(t) so HBM/L2 latency hides
// under MFMA; __syncthreads' vmcnt(0) drain lands AFTER the compute.
#define BM 128
#define BN 128
#define BK 32
#define NKT 32   // 1024 / 32

__global__ __launch_bounds__(256, 2) void gemm_kernel(const ushort_t* __restrict__ Xb,
                                                      const ushort_t* __restrict__ Wt,
                                                      const float* __restrict__ bseed,
                                                      const float* __restrict__ bsig,
                                                      const float* __restrict__ asig,
                                                      float* __restrict__ out) {
    // double buffer: [buf][A(4096) | B(4096)] ushorts = 32 KB total
    __shared__ ushort_t lds[16384];
    ushort_t* At0 = lds;
    ushort_t* Bt0 = lds + 4096;
    ushort_t* At1 = lds + 8192;
    ushort_t* Bt1 = lds + 12288;

    const int t = threadIdx.x;        // 0..255
    const int wv = t >> 6;
    const int lane = t & 63;

    // XCD-aware swizzle (512 blocks, 512%8==0 -> bijective)
    const int orig = blockIdx.x;
    const int g = orig & 7;           // XCD id under round-robin dispatch
    const int within = orig >> 3;     // 0..63 within this XCD
    const int rb = g * 8 + (within >> 3);   // row-block 0..63 (8 per XCD)
    const int cb = within & 7;              // col-block 0..7
    const int brow = rb * BM;
    const int bcol = cb * BN;

    // staging: thread t covers 8 contiguous bf16 (16B); 4 threads per 32-elem row
    const int r0 = t >> 2;            // 0..63
    const int kc = (t & 3) * 8;       // 0,8,16,24
    const ushort_t* gA0 = Xb + (size_t)(brow + r0) * 1024 + kc;
    const ushort_t* gA1 = Xb + (size_t)(brow + 64 + r0) * 1024 + kc;
    const ushort_t* gB0 = Wt + (size_t)(bcol + r0) * 1024 + kc;
    const ushort_t* gB1 = Wt + (size_t)(bcol + 64 + r0) * 1024 + kc;

    f32x4 acc[4][4];
    #pragma unroll
    for (int i = 0; i < 4; ++i)
        #pragma unroll
        for (int j = 0; j < 4; ++j) acc[i][j] = (f32x4){0.f, 0.f, 0.f, 0.f};

    const int wr = (wv >> 1) * 64;    // wave row origin in tile
    const int wcn = (wv & 1) * 64;    // wave col origin in tile
    const int fr = lane & 15;         // fragment row/col within 16
    const int kg = (lane >> 4) * 8;   // k-group offset

    // wave-uniform LDS staging bases (lane*16B implicit in global_load_lds)
    const int sA = wv * 512;          // within A half: wave wv covers rows [wv*16, wv*16+16)
    const int sA2 = 2048 + wv * 512;  // rows 64..127
#define STAGE(Abuf, Bbuf, ko)                                  \
    do {                                                       \
        async16((Abuf) + sA,  gA0 + (ko));                     \
        async16((Abuf) + sA2, gA1 + (ko));                     \
        async16((Bbuf) + sA,  gB0 + (ko));                     \
        async16((Bbuf) + sA2, gB1 + (ko));                     \
    } while (0)

#define COMPUTE(Abuf, Bbuf)                                                        \
    do {                                                                           \
        bf16x8 af[4], bf[4];                                                       \
        _Pragma("unroll")                                                          \
        for (int mi = 0; mi < 4; ++mi)                                             \
            af[mi] = *(const bf16x8*)&(Abuf)[(wr + mi * 16 + fr) * BK + kg];       \
        _Pragma("unroll")                                                          \
        for (int ni = 0; ni < 4; ++ni)                                             \
            bf[ni] = *(const bf16x8*)&(Bbuf)[(wcn + ni * 16 + fr) * BK + kg];      \
        _Pragma("unroll")                                                          \
        for (int mi = 0; mi < 4; ++mi)                                             \
            _Pragma("unroll")                                                      \
            for (int ni = 0; ni < 4; ++ni)                                         \
                acc[mi][ni] = __builtin_amdgcn_mfma_f32_16x16x32_bf16(             \
                    af[mi], bf[ni], acc[mi][ni], 0, 0, 0);                         \
    } while (0)

    // prologue
    STAGE(At0, Bt0, 0);
    __syncthreads();
    // main: 15 double-iterations, static buffer names (no runtime LDS indexing)
    for (int it = 0; it < 15; ++it) {
        STAGE(At1, Bt1, (2 * it + 1) * BK);   // issue loads FIRST
        COMPUTE(At0, Bt0);                    // latency hides under MFMA
        __syncthreads();                      // drain: buf1 staged, buf0 reads done
        STAGE(At0, Bt0, (2 * it + 2) * BK);
        COMPUTE(At1, Bt1);
        __syncthreads();
    }
    // tail: K-steps 30, 31
    STAGE(At1, Bt1, 31 * BK);
    COMPUTE(At0, Bt0);
    __syncthreads();
    COMPUTE(At1, Bt1);

    // epilogue: bias + activation mixture
    float bs0, bs1, as0, as1;
    softmax2(bsig, bs0, bs1);
    softmax2(asig, as0, as1);

    #pragma unroll
    for (int ni = 0; ni < 4; ++ni) {
        int col = bcol + wcn + ni * 16 + fr;
        float bias = bs0 * bseed[col];
        #pragma unroll
        for (int mi = 0; mi < 4; ++mi) {
            int row = brow + wr + mi * 16 + (lane >> 4) * 4;
            #pragma unroll
            for (int r = 0; r < 4; ++r) {
                float v = acc[mi][ni][r] + bias;
                out[(size_t)(row + r) * 1024 + col] = as0 * v + as1 * fmaxf(v, 0.f);
            }
        }
    }
#undef STAGE
#undef COMPUTE
}

// ---------------- fallback (only if workspace too small): naive fp32 ----------------
__global__ __launch_bounds__(256) void naive_kernel(const float* __restrict__ x,
                                                    const float* __restrict__ Wseed,
                                                    const float* __restrict__ bseed,
                                                    const float* __restrict__ Wsig,
                                                    const float* __restrict__ bsig,
                                                    const float* __restrict__ asig,
                                                    float* __restrict__ out) {
    int idx = blockIdx.x * 256 + threadIdx.x;
    int b = idx >> 10, o = idx & 1023;
    float ws0, ws1, bs0, bs1, as0, as1;
    softmax2(Wsig, ws0, ws1);
    softmax2(bsig, bs0, bs1);
    softmax2(asig, as0, as1);
    float s = 0.f;
    const float* xr = x + (size_t)b * 1024;
    for (int k = 0; k < 1024; ++k) {
        float wc = ws0 * Wseed[((size_t)k << 10) + o] + ws1 * toep_val(Wseed, k, o);
        s += xr[k] * wc;
    }
    float v = s + bs0 * bseed[o];
    out[idx] = as0 * v + as1 * fmaxf(v, 0.f);
}

extern "C" void kernel_launch(void* const* d_in, const int* in_sizes, int n_in,
                              void* d_out, int out_size, void* d_ws, size_t ws_size,
                              hipStream_t stream) {
    const float* x     = (const float*)d_in[0];
    const float* Wseed = (const float*)d_in[1];
    const float* bseed = (const float*)d_in[2];
    const float* Wsig  = (const float*)d_in[3];
    const float* bsig  = (const float*)d_in[4];
    const float* Asig  = (const float*)d_in[5];
    float* out = (float*)d_out;

    const size_t need = (2u << 20) + (16u << 20) + 1024;
    if (ws_size < need) {
        naive_kernel<<<dim3(8192 * 1024 / 256), dim3(256), 0, stream>>>(
            x, Wseed, bseed, Wsig, bsig, Asig, out);
        return;
    }

    ushort_t* Wt = (ushort_t*)d_ws;                         // 2 MB: W_core^T bf16 [1024][1024]
    ushort_t* Xb = (ushort_t*)((char*)d_ws + (2u << 20));   // 16 MB: x bf16 [8192][1024]

    prep_kernel<<<dim3(4096 + 256), dim3(256), 0, stream>>>(x, Wseed, Wsig, Xb, Wt);
    gemm_kernel<<<dim3(512), dim3(256), 0, stream>>>(Xb, Wt, bseed, bsig, Asig, out);
}